// Round 1
// baseline (1129.982 us; speedup 1.0000x reference)
//
#include <hip/hip_runtime.h>

// ContinuousLearningLayer: pooled[i][j] = any_{k in [j-25, j+25]} (|in[i] - w[k]| < 0.1)
// in: 1024 fp32 (flattened (2,512)), w: 262144 fp32 (flattened (512,512))
// out: [1024, 262144] fp32 in {0,1}
//
// Strategy: bitset. ballot -> 64 predicate bits/instr; radius-25 binary dilation
// via log shift-OR over a 128-bit window; expand bits to coalesced float4 stores.
// Memory-bound on the 1.07 GB output write.

static constexpr int N_ROWS   = 1024;     // flattened input features
static constexpr int M_W      = 262144;   // flattened weights
static constexpr int CHUNK    = 16384;    // output elements per block
static constexpr int NWORDS   = CHUNK / 64;        // 256 dilated words per block
static constexpr int TOTW     = NWORDS + 2;        // +1 halo word each side
static constexpr float THRESH = 0.1f;

__global__ __launch_bounds__(256) void cll_kernel(const float* __restrict__ in,
                                                  const float* __restrict__ wm,
                                                  float* __restrict__ out) {
    __shared__ unsigned long long words[TOTW];   // raw predicate bits
    __shared__ unsigned long long dil[NWORDS];   // dilated bits

    const int tid  = threadIdx.x;
    const int wave = tid >> 6;
    const int lane = tid & 63;
    const int row  = blockIdx.y;
    const int chunkBase = blockIdx.x * CHUNK;

    const float x = in[row];

    // ---- Phase 1: predicate bits via ballot.
    // Array bit p (p = wIdx*64 + lane) corresponds to global weight index
    // j = chunkBase - 64 + p. Out-of-range j -> bit 0 (matches -inf padding:
    // window always holds >=26 valid elems, so max == any over valid ones).
    for (int wIdx = wave; wIdx < TOTW; wIdx += 4) {
        const int j = chunkBase - 64 + wIdx * 64 + lane;
        bool pred = false;
        if (j >= 0 && j < M_W) {
            pred = fabsf(wm[j] - x) < THRESH;
        }
        const unsigned long long b = __ballot(pred);
        if (lane == 0) words[wIdx] = b;
    }
    __syncthreads();

    // ---- Phase 2: radius-25 dilation, one 64-bit output word per thread.
    // Output word t covers outputs e = t*64 + i (global j = chunkBase + e).
    // Need stream bits [t*64 + 39, t*64 + 167) relative to array bit 0:
    //   y bit q = array bit (t*64 + 39 + q), q in [0,128)
    // result bit i = OR_{u=0..50} y bit (i+u)  == any over [j-25, j+25].
    {
        const int t = tid;  // 0..255 == NWORDS
        const unsigned long long lo  = words[t];
        const unsigned long long mid = words[t + 1];
        const unsigned long long hi  = words[t + 2];
        __uint128_t y = ((__uint128_t)(lo >> 39))
                      | ((__uint128_t)mid << 25)
                      | ((__uint128_t)hi << 89);
        __uint128_t z = y;
        z |= z >> 1;    // covers shifts 0..1
        z |= z >> 2;    // 0..3
        z |= z >> 4;    // 0..7
        z |= z >> 8;    // 0..15
        z |= z >> 16;   // 0..31
        z |= z >> 19;   // 0..50 (19 <= 32, so union is contiguous)
        dil[t] = (unsigned long long)z;
    }
    __syncthreads();

    // ---- Phase 3: expand bits -> fp32, coalesced float4 stores.
    float* orow = out + (long long)row * M_W + chunkBase;
    #pragma unroll
    for (int it = 0; it < CHUNK / 1024; ++it) {
        const int e = it * 1024 + tid * 4;               // aligned, 4 bits same word
        const unsigned long long wbits = dil[e >> 6];
        const unsigned b4 = (unsigned)(wbits >> (e & 63)) & 0xFu;
        float4 v;
        v.x = (float)(b4 & 1u);
        v.y = (float)((b4 >> 1) & 1u);
        v.z = (float)((b4 >> 2) & 1u);
        v.w = (float)((b4 >> 3) & 1u);
        *(float4*)(orow + e) = v;
    }
}

extern "C" void kernel_launch(void* const* d_in, const int* in_sizes, int n_in,
                              void* d_out, int out_size, void* d_ws, size_t ws_size,
                              hipStream_t stream) {
    const float* in  = (const float*)d_in[0];   // input_features (2,512) fp32
    const float* wm  = (const float*)d_in[1];   // weight_matrix (512,512) fp32
    float* out = (float*)d_out;                 // [1024, 262144] fp32

    dim3 grid(M_W / CHUNK, N_ROWS);             // (16, 1024) = 16384 blocks
    cll_kernel<<<grid, 256, 0, stream>>>(in, wm, out);
}